// Round 11
// baseline (1839.897 us; speedup 1.0000x reference)
//
#include <hip/hip_runtime.h>
#include <stdint.h>

// ---------------------------------------------------------------------------
// FixedPointLSTM (B=64, T=256, I=512, H=1024), fixed-point Q8.8 with hard
// activations. All fxp grid values are exactly representable in fp16; fp16
// MFMA with fp32 accumulate matches the numpy reference to ~1 grid step.
//
// R11: tagged handoff v2. h words are self-validating u32 = (t<<16)|h_fp16.
// Producers fire relaxed agent-scope 4B stores (no drain, no flag, no release
// on the critical path). Consumers stage with 8x 16B global_load_dwordx4
// sc0 sc1 (same transaction count as R10's proven staging, vs R8's failed
// 32x 4B) + vectorized tag check + per-quad retry (embedded vmcnt = natural
// throttle). The store->load data hop IS the synchronization: removes R10's
// drain-barrier -> flag-store -> flag-visibility -> poll chain (2 of 3 IC
// latencies per step). Flow control off-path: sflag=t+1 after staging, w0
// polls >= t concurrently with MFMA (validated R8). 2 barriers/step (was 3).
// Everything else = R10 (best verified: LDS layout, gate math, out-store
// placement, a255 residency pin, grp/rank decomposition).
// ---------------------------------------------------------------------------

typedef _Float16 h8 __attribute__((ext_vector_type(8)));
typedef _Float16 h4 __attribute__((ext_vector_type(4)));
typedef float f4 __attribute__((ext_vector_type(4)));
typedef unsigned long long u64;
typedef uint32_t u32x4 __attribute__((ext_vector_type(4)));

#define MFMA16(a, b, c) __builtin_amdgcn_mfma_f32_16x16x32_f16(a, b, c, 0, 0, 0)

__device__ __forceinline__ float fxp(float x) {
  float q = rintf(x * 256.0f) * 0.00390625f;
  return fminf(fmaxf(q, -128.0f), 127.99609375f);
}

// round-only: for values provably in [-128, 127.996] the clamp is a no-op.
__device__ __forceinline__ float fxp_rnd(float x) {
  return rintf(x * 256.0f) * 0.00390625f;
}

__device__ __forceinline__ float hsig(float x) {
  return fminf(fmaxf(x / 6.0f + 0.5f, 0.0f), 1.0f);  // IEEE div to match np
}

// ---- quantize fp32 -> fxp grid, store fp16 ---------------------------------
__global__ void qf16_kernel(const float* __restrict__ in,
                            _Float16* __restrict__ out, int n4) {
  int i = blockIdx.x * 256 + threadIdx.x;
  if (i < n4) {
    float4 v = ((const float4*)in)[i];
    h4 o;
    o[0] = (_Float16)fxp(v.x); o[1] = (_Float16)fxp(v.y);
    o[2] = (_Float16)fxp(v.z); o[3] = (_Float16)fxp(v.w);
    ((h4*)out)[i] = o;
  }
}

// quantize + transpose x: in [64][256][512] -> rows m = t*64+b, [16384][512]
__global__ void qx_kernel(const float* __restrict__ in,
                          _Float16* __restrict__ out) {
  int i4 = blockIdx.x * 256 + threadIdx.x;  // over 16384*128 float4s
  int col4 = i4 & 127;
  int row = i4 >> 7;  // b*256 + t
  int b = row >> 8, tt = row & 255;
  float4 v = ((const float4*)in)[i4];
  h4 o;
  o[0] = (_Float16)fxp(v.x); o[1] = (_Float16)fxp(v.y);
  o[2] = (_Float16)fxp(v.z); o[3] = (_Float16)fxp(v.w);
  ((h4*)out)[(size_t)((tt << 6) + b) * 128 + col4] = o;
}

__global__ void qf32_kernel(const float* __restrict__ in,
                            float* __restrict__ out, int n4) {
  int i = blockIdx.x * 256 + threadIdx.x;
  if (i < n4) {
    float4 v = ((const float4*)in)[i];
    float4 o;
    o.x = fxp(v.x); o.y = fxp(v.y); o.z = fxp(v.z); o.w = fxp(v.w);
    ((float4*)out)[i] = o;
  }
}

// h0 -> htag buffer 0 (tag = 0): [grp=8][buf=2][row=8][1024] u32
__global__ void qh0_kernel(const float* __restrict__ in,
                           uint32_t* __restrict__ htag) {
  int i4 = blockIdx.x * 256 + threadIdx.x;  // over 16384 float4s
  int b = i4 >> 8;                          // 256 float4 per batch row
  int col = (i4 & 255) << 2;
  int grp = b >> 3, row = b & 7;
  float4 v = ((const float4*)in)[i4];
  uint4 o;
  o.x = (uint32_t)__builtin_bit_cast(unsigned short, (_Float16)fxp(v.x));
  o.y = (uint32_t)__builtin_bit_cast(unsigned short, (_Float16)fxp(v.y));
  o.z = (uint32_t)__builtin_bit_cast(unsigned short, (_Float16)fxp(v.z));
  o.w = (uint32_t)__builtin_bit_cast(unsigned short, (_Float16)fxp(v.w));
  *(uint4*)(htag + (size_t)grp * 16384 + row * 1024 + col) = o;
}

// ---- async global->LDS helper (width 16B; LDS dest = wave-uniform base) ----
__device__ __forceinline__ void gload_lds16(const _Float16* g, _Float16* l) {
  __builtin_amdgcn_global_load_lds(
      (const __attribute__((address_space(1))) uint32_t*)g,
      (__attribute__((address_space(3))) uint32_t*)l, 16, 0, 0);
}

// ---------------------------------------------------------------------------
// gx = fxp(x_q @ w_ih_q^T + b_ih_q), packed [T=256][oct=8][rank=32][slot=128][8]
// fp16 (128 MB). slot = (w<<5)|(qh<<4)|(gate&1)<<3|(j&7); per-entry 8 fp16 =
// [tile0 r=0..3 | tile1 r=0..3], tile = gate>>1, r = b&3, qh = (b>>2)&1.
// ---------------------------------------------------------------------------
__global__ __launch_bounds__(256) void gemm_gx_kernel(
    const _Float16* __restrict__ Xq,   // [16384][512], m = t*64+b
    const _Float16* __restrict__ Wih,  // [4096][512]
    const float* __restrict__ bih,     // [4096]
    _Float16* __restrict__ gx)         // packed, see above
{
  __shared__ _Float16 As[128 * 32];
  __shared__ _Float16 Bs[128 * 32];
  const int tid = threadIdx.x;
  const int lane = tid & 63;
  const int w = tid >> 6;
  const int wm = (w >> 1) * 64;
  const int wn = (w & 1) * 64;
  const int m0 = blockIdx.x * 128;
  const int n0 = blockIdx.y * 128;
  const int cl = lane & 15, q = lane >> 4;

  f4 acc[4][4] = {};

  for (int k0 = 0; k0 < 512; k0 += 32) {
#pragma unroll
    for (int i = 0; i < 2; i++) {
      int idx = i * 256 + tid;
      int row = idx >> 2;
      int kc = (idx & 3) << 3;
      int wbase = (i * 256 + (tid & 192)) << 3;  // wave-uniform LDS base
      gload_lds16(Xq + (size_t)(m0 + row) * 512 + k0 + kc, As + wbase);
      gload_lds16(Wih + (size_t)(n0 + row) * 512 + k0 + kc, Bs + wbase);
    }
    __syncthreads();
    h8 af[4], bf[4];
#pragma unroll
    for (int mt = 0; mt < 4; mt++)
      af[mt] = *(const h8*)(As + (wm + mt * 16 + cl) * 32 + q * 8);
#pragma unroll
    for (int nt = 0; nt < 4; nt++)
      bf[nt] = *(const h8*)(Bs + (wn + nt * 16 + cl) * 32 + q * 8);
#pragma unroll
    for (int mt = 0; mt < 4; mt++)
#pragma unroll
      for (int nt = 0; nt < 4; nt++)
        acc[mt][nt] = MFMA16(af[mt], bf[nt], acc[mt][nt]);
    __syncthreads();
  }

  const int g = n0 >> 10;  // whole n-block lies in one gate
  const int tile = g >> 1, g1 = g & 1;
#pragma unroll
  for (int nt = 0; nt < 4; nt++) {
    const int n = n0 + wn + nt * 16 + cl;
    const float bv = bih[n];
    const int j = n & 1023;
    const int rank = j >> 5, wq = (j >> 3) & 3, c7 = j & 7;
#pragma unroll
    for (int mt = 0; mt < 4; mt++) {
      const int m = m0 + wm + mt * 16 + q * 4;  // 4-aligned
      const int b = m & 63, tt = m >> 6;
      const int oct = b >> 3, qh = (b >> 2) & 1;
      const int slot = (wq << 5) | (qh << 4) | (g1 << 3) | c7;
      h4 pk;
#pragma unroll
      for (int r = 0; r < 4; r++) pk[r] = (_Float16)fxp(acc[mt][nt][r] + bv);
      *(h4*)(gx + ((((size_t)tt * 8 + oct) * 32 + rank) * 128 + slot) * 8 +
             tile * 4) = pk;
    }
  }
}

// ---------------------------------------------------------------------------
// Persistent recurrence. 256 blocks x 256 threads, a255 pin -> 1 block/CU ->
// all blocks co-resident. Block = (grp = blockIdx&7, rank = blockIdx>>3);
// group owns batch rows 8g..8g+7; rank owns h-cols rank*32..+31 x 4 gates
// (128 W_hh rows in regs). Per step:
//   gx prefetch -> stage buffer t&1 with tag-retry (8x 16B sc0 sc1 loads,
//   expect tag t) -> LDS (R10 layout) -> barrier B (+tid0 sflag=t+1;
//   w0 flow-polls peers staged >= t, concurrent with MFMA) -> MFMA ->
//   gates -> barrier C (hs consumed, flow-poll done) -> tagged h stores
//   (tag t+1, fire-and-forget) + out stores.
// ---------------------------------------------------------------------------
__global__ __launch_bounds__(256, 1) void lstm_kernel(
    const _Float16* __restrict__ Whh,  // [4096][1024] quantized
    const float* __restrict__ bhh,     // [4096] quantized
    const _Float16* __restrict__ gx,   // packed [256][8][32][128][8]
    const float* __restrict__ c0,      // [64][1024]
    uint32_t* __restrict__ htag,       // [8][2][8][1024] tagged h words
    float* __restrict__ out,           // [64][256][1024] ++ h_n ++ c_n
    unsigned* __restrict__ sflag)      // [8][32] staged-step counters
{
  // Residency pin: force total regs/wave > 256 -> 1 wave/SIMD -> 1 block/CU.
  asm volatile("v_accvgpr_write_b32 a255, 0" ::: "a255");

  const int tid = threadIdx.x;
  const int lane = tid & 63;
  const int w = tid >> 6;
  const int cl = lane & 15, q = lane >> 4;
  const int g01 = (lane >> 3) & 1;
  const int c7 = lane & 7;

  const int grp = blockIdx.x & 7;    // batch octet
  const int rank = blockIdx.x >> 3;  // 32-column slice owner

  const int jbase = (rank << 5) + (w << 3);         // block/wave col base
  const int row0 = (g01 << 10) + jbase + c7;        // gates i/f
  const int row1 = ((g01 + 2) << 10) + jbase + c7;  // gates g/o

  // persistent B fragments: 2 tiles x 32 k-steps x 4 regs = 256 regs
  h8 B0[32], B1[32];
#pragma unroll
  for (int kt = 0; kt < 32; kt++) {
    B0[kt] = *(const h8*)(Whh + (size_t)row0 * 1024 + (kt << 5) + (q << 3));
    B1[kt] = *(const h8*)(Whh + (size_t)row1 * 1024 + (kt << 5) + (q << 3));
  }
  const float bh0 = bhh[row0], bh1 = bhh[row1];
  const int jc = jbase + c7;        // h column 0..1023
  const int lrow = ((q & 1) << 2);  // local batch row base (valid q<2)
  const bool writer = ((lane & 8) == 0) && (q < 2);

  float c_st[4], h_last[4];
#pragma unroll
  for (int r = 0; r < 4; r++) {
    c_st[r] = c0[((grp << 3) + lrow + r) * 1024 + jc];
    h_last[r] = 0.0f;
  }

  // LDS h stage (R10 layout, verified): 8 rows x 1032 halves. Thread
  // (row=tid>>5, c=tid&31) holds quads c+32j of its row; LDS write at
  // row*1032 + 4c + 128j halves (4-way banks); fragment read arow*1032 +
  // kt*32 + q*8 (conflict-free).
  __shared__ alignas(16) _Float16 hs[8 * 1032];
  const int arow = cl & 7;
  _Float16* ldst = hs + (tid >> 5) * 1032 + ((tid & 31) << 2);

  unsigned* myflag = sflag + (grp << 5) + rank;
  const unsigned* pollp = sflag + (grp << 5) + (lane & 31);

  for (int t = 0; t < 256; t++) {
    // prefetch gx_t: one coalesced 16B load per lane (overlaps stage retry)
    const h8 gv8 = *(const h8*)(
        gx +
        ((((size_t)t * 8 + grp) * 32 + rank) * 128 + ((w << 5) | (lane & 31))) *
            8);

    // ---- stage h_t with per-quad tag retry (single IC hop) ----
    {
      const uint32_t* srcp = htag + ((size_t)grp * 2 + (t & 1)) * 8192 +
                             ((tid >> 5) << 10) + ((tid & 31) << 2);
      u32x4 v0, v1, v2, v3, v4, v5, v6, v7;
      asm volatile(
          "global_load_dwordx4 %0, %8, off sc0 sc1\n\t"
          "global_load_dwordx4 %1, %8, off offset:512 sc0 sc1\n\t"
          "global_load_dwordx4 %2, %8, off offset:1024 sc0 sc1\n\t"
          "global_load_dwordx4 %3, %8, off offset:1536 sc0 sc1\n\t"
          "global_load_dwordx4 %4, %8, off offset:2048 sc0 sc1\n\t"
          "global_load_dwordx4 %5, %8, off offset:2560 sc0 sc1\n\t"
          "global_load_dwordx4 %6, %8, off offset:3072 sc0 sc1\n\t"
          "global_load_dwordx4 %7, %8, off offset:3584 sc0 sc1\n\t"
          "s_waitcnt vmcnt(0)"
          : "=&v"(v0), "=&v"(v1), "=&v"(v2), "=&v"(v3), "=&v"(v4), "=&v"(v5),
            "=&v"(v6), "=&v"(v7)
          : "v"(srcp)
          : "memory");
      const uint32_t tgs = (uint32_t)t << 16;
#define QBAD(vq) \
  ((((vq[0] ^ tgs) | (vq[1] ^ tgs) | (vq[2] ^ tgs) | (vq[3] ^ tgs)) >> 16) != 0)
#define QRELOAD(vq, OFF)                                                  \
  if (__ballot(QBAD(vq)) != 0ull) {                                       \
    asm volatile("global_load_dwordx4 %0, %1, off offset:" #OFF           \
                 " sc0 sc1\n\ts_waitcnt vmcnt(0)"                         \
                 : "=&v"(vq) : "v"(srcp) : "memory");                     \
  }
      int it = 0;
      for (;;) {
        unsigned m = (QBAD(v0) ? 1u : 0u) | (QBAD(v1) ? 2u : 0u) |
                     (QBAD(v2) ? 4u : 0u) | (QBAD(v3) ? 8u : 0u) |
                     (QBAD(v4) ? 16u : 0u) | (QBAD(v5) ? 32u : 0u) |
                     (QBAD(v6) ? 64u : 0u) | (QBAD(v7) ? 128u : 0u);
        if (__ballot(m != 0u) == 0ull) break;
        if (++it > (1 << 14)) break;  // hang insurance (loudly wrong)
        QRELOAD(v0, 0)
        QRELOAD(v1, 512)
        QRELOAD(v2, 1024)
        QRELOAD(v3, 1536)
        QRELOAD(v4, 2048)
        QRELOAD(v5, 2560)
        QRELOAD(v6, 3072)
        QRELOAD(v7, 3584)
      }
#undef QRELOAD
#undef QBAD
#define QPACK(vq)                                                      \
  ((u64)(vq[0] & 0xFFFFu) | ((u64)(vq[1] & 0xFFFFu) << 16) |           \
   ((u64)(vq[2] & 0xFFFFu) << 32) | ((u64)(vq[3] & 0xFFFFu) << 48))
      *(u64*)(ldst + 0 * 128) = QPACK(v0);
      *(u64*)(ldst + 1 * 128) = QPACK(v1);
      *(u64*)(ldst + 2 * 128) = QPACK(v2);
      *(u64*)(ldst + 3 * 128) = QPACK(v3);
      *(u64*)(ldst + 4 * 128) = QPACK(v4);
      *(u64*)(ldst + 5 * 128) = QPACK(v5);
      *(u64*)(ldst + 6 * 128) = QPACK(v6);
      *(u64*)(ldst + 7 * 128) = QPACK(v7);
#undef QPACK
    }
    __syncthreads();  // barrier B: hs fully staged

    if (tid == 0)
      __hip_atomic_store(myflag, (unsigned)(t + 1), __ATOMIC_RELAXED,
                         __HIP_MEMORY_SCOPE_AGENT);
    // flow control, off critical path (overlaps peers' MFMA): before step
    // t's h stores overwrite buffer (t+1)&1 (holding h_{t-1}), confirm all
    // ranks staged h_{t-1} (sflag >= t). Usually satisfied a step early.
    if (w == 0 && t) {
      const unsigned need = (unsigned)t;
      int it = 0;
      for (;;) {
        unsigned v = __hip_atomic_load(pollp, __ATOMIC_RELAXED,
                                       __HIP_MEMORY_SCOPE_AGENT);
        if (__ballot(v >= need) == ~0ull) break;
        if (++it > (1 << 14)) break;
        __builtin_amdgcn_s_sleep(1);
      }
    }

    f4 a0 = {}, a1 = {}, a2 = {}, a3 = {};
#pragma unroll
    for (int kt = 0; kt < 32; kt++) {
      h8 av = *(const h8*)(hs + arow * 1032 + (kt << 5) + (q << 3));
      if (kt & 1) { a1 = MFMA16(av, B0[kt], a1); a3 = MFMA16(av, B1[kt], a3); }
      else        { a0 = MFMA16(av, B0[kt], a0); a2 = MFMA16(av, B1[kt], a2); }
    }
    f4 g0 = a0 + a1;
    f4 g1 = a2 + a3;

#pragma unroll
    for (int r = 0; r < 4; r++) {
      float gv0 = fxp((float)gv8[r] + fxp(g0[r] + bh0));      // i or f
      float gv1 = fxp((float)gv8[4 + r] + fxp(g1[r] + bh1));  // g or o
      float s0 = fxp_rnd(hsig(gv0));                        // in [0,1]
      float s1t = fxp_rnd(fminf(fmaxf(gv1, -1.0f), 1.0f));  // in [-1,1]
      float s1s = fxp_rnd(hsig(gv1));
      float s1 = (lane & 8) ? s1s : s1t;
      float p0 = __shfl_xor(s0, 8);
      float p1 = __shfl_xor(s1, 8);
      float iv = writer ? s0 : p0;
      float fv = writer ? p0 : s0;
      float gv = writer ? s1 : p1;
      float ov = writer ? p1 : s1;
      float cn = fxp(fv * c_st[r] + iv * gv);
      c_st[r] = cn;
      h_last[r] = fxp_rnd(ov * fminf(fmaxf(cn, -1.0f), 1.0f));  // in [-1,1]
    }

    // barrier C: (a) hs consumed by all waves before next step's staging,
    // (b) w0's flow-control poll done before any h store below.
    __syncthreads();

    if (writer) {
      uint32_t* dst = htag + ((size_t)grp * 2 + ((t + 1) & 1)) * 8192;
      const uint32_t tagw = (uint32_t)(t + 1) << 16;
#pragma unroll
      for (int r = 0; r < 4; r++) {
        uint32_t word =
            tagw |
            (uint32_t)__builtin_bit_cast(unsigned short, (_Float16)h_last[r]);
        __hip_atomic_store(dst + (lrow + r) * 1024 + jc, word, __ATOMIC_RELAXED,
                           __HIP_MEMORY_SCOPE_AGENT);
      }
#pragma unroll
      for (int r = 0; r < 4; r++)
        __builtin_nontemporal_store(
            h_last[r],
            &out[((size_t)((grp << 3) + lrow + r) * 256 + t) * 1024 + jc]);
    }
  }

  if (writer) {
#pragma unroll
    for (int r = 0; r < 4; r++) {
      out[16777216 + (size_t)((grp << 3) + lrow + r) * 1024 + jc] = h_last[r];
      out[16777216 + 65536 + (size_t)((grp << 3) + lrow + r) * 1024 + jc] =
          c_st[r];
    }
  }
}

// ---------------------------------------------------------------------------
extern "C" void kernel_launch(void* const* d_in, const int* in_sizes, int n_in,
                              void* d_out, int out_size, void* d_ws,
                              size_t ws_size, hipStream_t stream) {
  const float* x    = (const float*)d_in[0];
  const float* w_ih = (const float*)d_in[1];
  const float* w_hh = (const float*)d_in[2];
  const float* b_ih = (const float*)d_in[3];
  const float* b_hh = (const float*)d_in[4];
  const float* h0   = (const float*)d_in[5];
  const float* c0   = (const float*)d_in[6];
  float* out = (float*)d_out;

  // workspace layout (bytes); total ~156.3 MB. htag aliases wihq (dead after
  // the gemm; qh0 launches after gemm).
  char* ws = (char*)d_ws;
  unsigned* sflag = (unsigned*)ws;                    // [8][32] u32 = 1 KB
  _Float16* whhq  = (_Float16*)(ws + 264192);         // 8 MB
  _Float16* wihq  = (_Float16*)(ws + 8652800);        // 4 MB
  uint32_t* htag  = (uint32_t*)(ws + 8652800);        // 512 KB (after gemm)
  float*    bihq  = (float*)(ws + 12847104);          // 16 KB
  float*    bhhq  = (float*)(ws + 12863488);          // 16 KB
  _Float16* xq    = (_Float16*)(ws + 12879872);       // 16 MB
  _Float16* gxb   = (_Float16*)(ws + 29657088);       // 128 MB packed

  hipMemsetAsync(sflag, 0, 2048, stream);
  qf16_kernel<<<dim3(4096), 256, 0, stream>>>(w_hh, whhq, 4194304 / 4);
  qf16_kernel<<<dim3(2048), 256, 0, stream>>>(w_ih, wihq, 2097152 / 4);
  qx_kernel<<<dim3(8192), 256, 0, stream>>>(x, xq);
  qf32_kernel<<<dim3(4), 256, 0, stream>>>(b_ih, bihq, 4096 / 4);
  qf32_kernel<<<dim3(4), 256, 0, stream>>>(b_hh, bhhq, 4096 / 4);
  gemm_gx_kernel<<<dim3(128, 32), 256, 0, stream>>>(xq, wihq, bihq, gxb);
  qh0_kernel<<<dim3(64), 256, 0, stream>>>(h0, htag);  // after gemm: wihq dead
  lstm_kernel<<<dim3(256), 256, 0, stream>>>(whhq, bhhq, gxb, c0, htag, out,
                                             sflag);
}